// Round 4
// baseline (14237.926 us; speedup 1.0000x reference)
//
#include <hip/hip_runtime.h>

typedef _Float16 fp16_t;
typedef _Float16 v8h __attribute__((ext_vector_type(8)));
typedef float    v4f __attribute__((ext_vector_type(4)));

#define RELAX_LR 0.3f

// async global->LDS, 16B per lane. LDS dest = wave-uniform base + lane*16.
__device__ __forceinline__ void async_cp16(const void* g, void* l) {
    __builtin_amdgcn_global_load_lds(
        (const __attribute__((address_space(1))) void*)g,
        (__attribute__((address_space(3))) void*)l, 16, 0, 0);
}

// Fused split-K GEMM + last-block reduction job.
// GEMM: C_partial(z) = A1*B1t^T (concat K-space [0,K1)) ++ A2*B2t^T
// ([K1,K1+K2s)). Chunk z covers [z*CK,(z+1)*CK); K1 and CK are multiples of
// BK=64 so a BK-tile never straddles the section boundary.
// Epilogue (elected last block per output tile): sum z fp16 partial slices
// + (bias[col] OR fp32 extra[idx]), optional relax-update vs s_old, then
// either raw fp32 store (f32out, c1f mode) or clip + fp16 state store +
// optional stripped [1024,1000] fp32 finout.
struct GJob {
    const fp16_t *A1, *B1t, *A2, *B2t;
    fp16_t* part;
    unsigned int* cnt;          // one u32 per output tile, zeroed; reset by winner
    const float* bias;
    const float* extra;
    const fp16_t* s_old;
    fp16_t* outb;
    float* f32out;
    float* finout;
    int K1, K2s, CK, Ntot;
};

// ---------------------------------------------------------------------------
// Proven r0 GEMM core (2407 us session best): tile BM=128 x BN=128 x BK=64,
// 256 thr = 4 waves, each wave 64x64 (4x4 16x16x32 f16 MFMA), double-buffered
// 64 KB LDS -> 2 blocks/CU (8 waves/CU; BK=32/16-wave variant regressed 10%
// in r2, fewer waves regressed 19% earlier -> this point is the optimum).
// XCD-swizzled decode: blk%8 = XCD; z pinned per XCD -> ~3MB L2 working set.
// NEW vs r0: split-K reduce + epilogue folded in via last-block election
// (threadfence + device-scope atomic ticket), eliminating all standalone
// reduce dispatches (170 -> 89 dispatches on the critical path).
// ---------------------------------------------------------------------------
__global__ __launch_bounds__(256, 2) void gemm_splitk_kernel(GJob j0, GJob j1, int nb0)
{
    __shared__ __align__(16) fp16_t As[2][2][128][32];  // [stage][khalf][row][col]
    __shared__ __align__(16) fp16_t Bs[2][2][128][32];
    __shared__ int s_last;

    const int tid  = threadIdx.x;
    const int lane = tid & 63;
    const int w    = tid >> 6;         // wave 0..3
    const int wm   = w >> 1;           // m-half (64 rows)
    const int wn   = w & 1;            // n-half (64 cols)
    const int quad = lane >> 4;
    const int lrow = lane & 15;

    int bblk = blockIdx.x;
    const GJob j = (bblk < nb0) ? j0 : j1;       // block-uniform
    if (bblk >= nb0) bblk -= nb0;

    // swizzled decode: bblk%8 = XCD; c = (bn,z) combo pinned to one XCD.
    const int low3 = bblk & 7;
    const int g    = bblk >> 3;
    const int bm   = g & 7;
    const int c    = (g >> 3) * 8 + low3;   // 0..63
    int bn, z, zn;
    if (j.Ntot == 2048) { bn = c >> 2; z = c & 3; zn = 4; }   // 16 bn x 4 z
    else                { bn = c >> 3; z = c & 7; zn = 8; }   // 8 bn x 8 z
    const int k0 = z * j.CK;

    // staging: each cp16 = 16 rows x 32 fp16 (1 KB/wave), lane -> (row=lane/4,
    // col=(lane&3)*8) matches LDS base + lane*16. Wave w owns rows
    // [32w,32w+32) of A and B for both khalves: 8 cp16/wave per stage.
    const int sr = lane >> 2;
    const int sc = (lane & 3) * 8;
    const size_t rowA = (size_t)(bm * 128 + 32 * w + sr);
    const size_t rowB = (size_t)(bn * 128 + 32 * w + sr);
    const fp16_t* a1 = j.A1  + rowA * j.K1 + sc;
    const fp16_t* b1 = j.B1t + rowB * j.K1 + sc;
    const fp16_t* a2 = j.A2  ? j.A2  + rowA * j.K2s + sc : nullptr;
    const fp16_t* b2 = j.B2t ? j.B2t + rowB * j.K2s + sc : nullptr;
    const size_t s16a = (size_t)16 * j.K1;
    const size_t s16b = (size_t)16 * j.K2s;

    auto stage = [&](int buf, int kc) {
        const fp16_t *a0, *b0; size_t st;
        if (kc < j.K1) { a0 = a1 + kc;          b0 = b1 + kc;          st = s16a; }
        else           { a0 = a2 + (kc - j.K1); b0 = b2 + (kc - j.K1); st = s16b; }
        async_cp16(a0,           &As[buf][0][32 * w     ][0]);
        async_cp16(a0 + st,      &As[buf][0][32 * w + 16][0]);
        async_cp16(a0 + 32,      &As[buf][1][32 * w     ][0]);
        async_cp16(a0 + 32 + st, &As[buf][1][32 * w + 16][0]);
        async_cp16(b0,           &Bs[buf][0][32 * w     ][0]);
        async_cp16(b0 + st,      &Bs[buf][0][32 * w + 16][0]);
        async_cp16(b0 + 32,      &Bs[buf][1][32 * w     ][0]);
        async_cp16(b0 + 32 + st, &Bs[buf][1][32 * w + 16][0]);
    };

    v4f acc[4][4] = {};
    const int iters = j.CK >> 6;       // BK = 64

    stage(0, k0);                      // prologue: tile 0 -> buffer 0

    for (int it = 0; it < iters; ++it) {
        __syncthreads();   // drains vmcnt -> buf (it&1) ready; prior ds_reads done
        if (it + 1 < iters) stage((it + 1) & 1, k0 + (it + 1) * 64);
        const int cur = it & 1;
        #pragma unroll
        for (int h = 0; h < 2; ++h) {
            v8h af[4], bv[4];
            #pragma unroll
            for (int fm = 0; fm < 4; ++fm)
                af[fm] = *(const v8h*)&As[cur][h][wm * 64 + fm * 16 + lrow][quad * 8];
            #pragma unroll
            for (int fn = 0; fn < 4; ++fn)
                bv[fn] = *(const v8h*)&Bs[cur][h][wn * 64 + fn * 16 + lrow][quad * 8];
            #pragma unroll
            for (int fm = 0; fm < 4; ++fm)
                #pragma unroll
                for (int fn = 0; fn < 4; ++fn)
                    acc[fm][fn] = __builtin_amdgcn_mfma_f32_16x16x32_f16(
                        af[fm], bv[fn], acc[fm][fn], 0, 0, 0);
        }
    }

    // write fp16 partials. C/D layout: col = lane&15, row = quad*4 + reg.
    fp16_t* po = j.part + (size_t)z * 1024 * j.Ntot;
    const int rowbase = bm * 128 + wm * 64 + quad * 4;
    const int colbase = bn * 128 + wn * 64;
    #pragma unroll
    for (int fn = 0; fn < 4; ++fn) {
        const int col = colbase + fn * 16 + lrow;
        #pragma unroll
        for (int fm = 0; fm < 4; ++fm) {
            const int row = rowbase + fm * 16;
            #pragma unroll
            for (int r = 0; r < 4; ++r)
                po[(size_t)(row + r) * j.Ntot + col] = (fp16_t)acc[fm][fn][r];
        }
    }

    // ---- last-block election (threadFenceReduction pattern) ----
    __threadfence();                   // release my partial stores device-wide
    __syncthreads();                   // all threads' stores fenced
    if (tid == 0) {
        const int tile = bm * (j.Ntot >> 7) + bn;
        const unsigned int prev = atomicAdd(&j.cnt[tile], 1u);  // device scope
        const int last = (prev == (unsigned int)(zn - 1));
        if (last)                      // all z arrived; reset for next dispatch
            __hip_atomic_store(&j.cnt[tile], 0u, __ATOMIC_RELAXED,
                               __HIP_MEMORY_SCOPE_AGENT);
        s_last = last;
    }
    __syncthreads();
    if (!s_last) return;
    __threadfence();                   // acquire: see other XCDs' partials

    // ---- reduce + epilogue for this 128x128 tile ----
    // mapping: 16 threads/row (256B contiguous, coalesced), 16 rows/pass,
    // 8 passes. col chunk is pass-invariant -> hoist bias load.
    const int lcol = (tid & 15) * 8;
    const int gcol = bn * 128 + lcol;
    float bb[8];
    if (!j.extra) {
        const float4 b0 = *(const float4*)(j.bias + gcol);
        const float4 b1v = *(const float4*)(j.bias + gcol + 4);
        bb[0] = b0.x; bb[1] = b0.y; bb[2] = b0.z; bb[3] = b0.w;
        bb[4] = b1v.x; bb[5] = b1v.y; bb[6] = b1v.z; bb[7] = b1v.w;
    }
    const size_t zstr = (size_t)1024 * j.Ntot;
    #pragma unroll
    for (int pp = 0; pp < 8; ++pp) {
        const int grow = bm * 128 + pp * 16 + (tid >> 4);
        const size_t e = (size_t)grow * j.Ntot + gcol;
        float v[8];
        {
            const v8h p0 = *(const v8h*)(j.part + e);
            #pragma unroll
            for (int k = 0; k < 8; ++k) v[k] = (float)p0[k];
        }
        for (int zz = 1; zz < zn; ++zz) {
            const v8h pz = *(const v8h*)(j.part + (size_t)zz * zstr + e);
            #pragma unroll
            for (int k = 0; k < 8; ++k) v[k] += (float)pz[k];
        }
        if (j.extra) {
            const float4 e0 = *(const float4*)(j.extra + e);
            const float4 e1 = *(const float4*)(j.extra + e + 4);
            v[0] += e0.x; v[1] += e0.y; v[2] += e0.z; v[3] += e0.w;
            v[4] += e1.x; v[5] += e1.y; v[6] += e1.z; v[7] += e1.w;
        } else {
            #pragma unroll
            for (int k = 0; k < 8; ++k) v[k] += bb[k];
        }
        if (j.s_old) {
            const v8h so = *(const v8h*)(j.s_old + e);
            #pragma unroll
            for (int k = 0; k < 8; ++k) {
                const float s = (float)so[k];
                v[k] = s + RELAX_LR * (v[k] - s);
            }
        }
        if (j.f32out) {                // c1f mode: raw fp32, no clip
            float4 o0 = {v[0], v[1], v[2], v[3]};
            float4 o1 = {v[4], v[5], v[6], v[7]};
            *(float4*)(j.f32out + e)     = o0;
            *(float4*)(j.f32out + e + 4) = o1;
        } else {
            #pragma unroll
            for (int k = 0; k < 8; ++k) v[k] = fminf(fmaxf(v[k], 0.f), 1.f);
            v8h h;
            #pragma unroll
            for (int k = 0; k < 8; ++k) h[k] = (fp16_t)v[k];
            *(v8h*)(j.outb + e) = h;
            if (j.finout && gcol < 1000) {   // Ntot==1024 here; 1000%8==0
                float* o = j.finout + (size_t)grow * 1000 + gcol;
                float4 o0 = {v[0], v[1], v[2], v[3]};
                float4 o1 = {v[4], v[5], v[6], v[7]};
                *(float4*)o       = o0;
                *(float4*)(o + 4) = o1;
            }
        }
    }
}

// fp32 W [R,C] -> fp16 Wb [Rp,Cp] (optional) + fp16 WbT [Cp,Rp], zero-padded.
__global__ void conv_w_kernel(const float* __restrict__ W, int R, int C,
                              fp16_t* Wb, fp16_t* __restrict__ WbT,
                              int Rp, int Cp)
{
    __shared__ float t[32][33];
    const int tx = threadIdx.x & 31;
    const int ty = threadIdx.x >> 5;   // 0..7
    const int r0 = blockIdx.y * 32;
    const int c0 = blockIdx.x * 32;
    #pragma unroll
    for (int i = 0; i < 4; ++i) {
        const int r = r0 + ty + i * 8;
        const int c = c0 + tx;
        float v = 0.f;
        if (r < R && c < C) v = W[(size_t)r * C + c];
        t[ty + i * 8][tx] = v;
    }
    __syncthreads();
    if (Wb) {
        #pragma unroll
        for (int i = 0; i < 4; ++i) {
            const int r = r0 + ty + i * 8;
            const int c = c0 + tx;
            if (r < Rp && c < Cp) Wb[(size_t)r * Cp + c] = (fp16_t)t[ty + i * 8][tx];
        }
    }
    #pragma unroll
    for (int i = 0; i < 4; ++i) {
        const int cc = c0 + ty + i * 8;
        const int rr = r0 + tx;
        if (cc < Cp && rr < Rp) WbT[(size_t)cc * Rp + rr] = (fp16_t)t[tx][ty + i * 8];
    }
}

__global__ void conv_x_kernel(const float* __restrict__ x,
                              fp16_t* __restrict__ xb, fp16_t* __restrict__ rxb, int n)
{
    const int i = blockIdx.x * blockDim.x + threadIdx.x;
    if (i < n) {
        const float v = x[i];
        xb[i]  = (fp16_t)v;
        rxb[i] = (fp16_t)fminf(fmaxf(v, 0.f), 1.f);
    }
}

__global__ void pad_b4_kernel(const float* __restrict__ b4, float* __restrict__ b4p)
{
    const int i = blockIdx.x * blockDim.x + threadIdx.x;
    if (i < 1024) b4p[i] = (i < 1000) ? b4[i] : 0.f;
}

__global__ void zero_cnt_kernel(unsigned int* __restrict__ c, int n)
{
    const int i = blockIdx.x * blockDim.x + threadIdx.x;
    if (i < n) c[i] = 0u;
}

extern "C" void kernel_launch(void* const* d_in, const int* in_sizes, int n_in,
                              void* d_out, int out_size, void* d_ws, size_t ws_size,
                              hipStream_t stream)
{
    const float* x  = (const float*)d_in[0];
    const float* W0 = (const float*)d_in[1];
    const float* W1 = (const float*)d_in[2];
    const float* W2 = (const float*)d_in[3];
    const float* W3 = (const float*)d_in[4];
    const float* b1 = (const float*)d_in[5];
    const float* b2 = (const float*)d_in[6];
    const float* b3 = (const float*)d_in[7];
    const float* b4 = (const float*)d_in[8];
    float* out = (float*)d_out;

    char* p = (char*)d_ws;
    auto alloc = [&](size_t bytes) {
        char* q = p;
        p += (bytes + 255) & ~(size_t)255;
        return q;
    };

    fp16_t* xb    = (fp16_t*)alloc((size_t)1024 * 2048 * 2);
    fp16_t* rxb   = (fp16_t*)alloc((size_t)1024 * 2048 * 2);
    fp16_t* Wb1   = (fp16_t*)alloc((size_t)2048 * 2048 * 2);
    fp16_t* Wb2   = (fp16_t*)alloc((size_t)2048 * 2048 * 2);
    fp16_t* Wb3   = (fp16_t*)alloc((size_t)2048 * 1024 * 2);   // padded cols
    fp16_t* WbT0  = (fp16_t*)alloc((size_t)2048 * 2048 * 2);
    fp16_t* WbT1  = (fp16_t*)alloc((size_t)2048 * 2048 * 2);
    fp16_t* WbT2  = (fp16_t*)alloc((size_t)2048 * 2048 * 2);
    fp16_t* WbT3  = (fp16_t*)alloc((size_t)1024 * 2048 * 2);   // padded rows
    fp16_t* s1b   = (fp16_t*)alloc((size_t)1024 * 2048 * 2);
    fp16_t* s2b   = (fp16_t*)alloc((size_t)1024 * 2048 * 2);
    fp16_t* s3b   = (fp16_t*)alloc((size_t)1024 * 2048 * 2);
    fp16_t* s4b   = (fp16_t*)alloc((size_t)1024 * 1024 * 2);
    float*  b4p   = (float*)alloc(1024 * 4);
    float*  c1f   = (float*)alloc((size_t)1024 * 2048 * 4);    // hoisted b1+rho(x)@W0
    fp16_t* partA = (fp16_t*)alloc((size_t)8 * 1024 * 1024 * 2); // 16 MB (Ntot=1024 jobs)
    fp16_t* partB = (fp16_t*)alloc((size_t)4 * 1024 * 2048 * 2); // 16 MB (Ntot=2048 jobs)
    unsigned int* cntB = (unsigned int*)alloc(128 * 4);        // 8x16 tiles
    unsigned int* cntA = (unsigned int*)alloc(64 * 4);         // 8x8 tiles
    (void)ws_size; (void)in_sizes; (void)n_in; (void)out_size;

    // --- setup conversions ---
    conv_x_kernel<<<(1024 * 2048 + 255) / 256, 256, 0, stream>>>(x, xb, rxb, 1024 * 2048);
    pad_b4_kernel<<<4, 256, 0, stream>>>(b4, b4p);
    zero_cnt_kernel<<<1, 256, 0, stream>>>(cntB, 192);   // cntB and cntA contiguous
    conv_w_kernel<<<dim3(64, 64), 256, 0, stream>>>(W0, 2048, 2048, nullptr, WbT0, 2048, 2048);
    conv_w_kernel<<<dim3(64, 64), 256, 0, stream>>>(W1, 2048, 2048, Wb1, WbT1, 2048, 2048);
    conv_w_kernel<<<dim3(64, 64), 256, 0, stream>>>(W2, 2048, 2048, Wb2, WbT2, 2048, 2048);
    conv_w_kernel<<<dim3(32, 64), 256, 0, stream>>>(W3, 2048, 1000, Wb3, WbT3, 2048, 1024);

    const dim3 blk(256);

    // --- fused jobs: {A1,B1t,A2,B2t, part,cnt, bias,extra,s_old, outb,f32out,finout,
    //                  K1,K2s,CK,Ntot} ---
    const GJob jC1 = { rxb, WbT0, nullptr, nullptr, partB, cntB, b1,  nullptr, nullptr,
                       nullptr, c1f, nullptr, 2048, 0,    512,  2048 };
    const GJob jI1 = { xb,  WbT0, nullptr, nullptr, partB, cntB, b1,  nullptr, nullptr,
                       s1b, nullptr, nullptr, 2048, 0,    512,  2048 };
    const GJob jI2 = { s1b, WbT1, nullptr, nullptr, partB, cntB, b2,  nullptr, nullptr,
                       s2b, nullptr, nullptr, 2048, 0,    512,  2048 };
    const GJob jI3 = { s2b, WbT2, nullptr, nullptr, partB, cntB, b3,  nullptr, nullptr,
                       s3b, nullptr, nullptr, 2048, 0,    512,  2048 };
    const GJob jI4 = { s3b, WbT3, nullptr, nullptr, partA, cntA, b4p, nullptr, nullptr,
                       s4b, nullptr, nullptr, 2048, 0,    256,  1024 };
    const GJob jL1 = { s2b, Wb1,  nullptr, nullptr, partB, cntB, nullptr, c1f, s1b,
                       s1b, nullptr, nullptr, 2048, 0,    512,  2048 };
    const GJob jL2 = { s1b, WbT1, s3b, Wb2,         partB, cntB, b2,  nullptr, s2b,
                       s2b, nullptr, nullptr, 2048, 2048, 1024, 2048 };
    const GJob jL3 = { s2b, WbT2, s4b, Wb3,         partB, cntB, b3,  nullptr, s3b,
                       s3b, nullptr, nullptr, 2048, 1024, 768,  2048 }; // chunk 2 crosses at 64-boundary
    const GJob jL4 = { s3b, WbT3, nullptr, nullptr, partA, cntA, b4p, nullptr, s4b,
                       s4b, nullptr, nullptr, 2048, 0,    256,  1024 };
    GJob jL4f = jL4; jL4f.finout = out;

    // --- hoisted layer-1 constant: c1f = b1 + rho(x)@W0 (once, reused 25x) ---
    gemm_splitk_kernel<<<512, blk, 0, stream>>>(jC1, jC1, 512);

    // --- feedforward init: s_l = clip(s_{l-1} @ W_{l-1} + b_l) ---
    gemm_splitk_kernel<<<512, blk, 0, stream>>>(jI1, jI1, 512);
    gemm_splitk_kernel<<<512, blk, 0, stream>>>(jI2, jI2, 512);
    gemm_splitk_kernel<<<512, blk, 0, stream>>>(jI3, jI3, 512);
    gemm_splitk_kernel<<<512, blk, 0, stream>>>(jI4, jI4, 512);

    // --- 25 Gauss-Seidel sweeps. Layer order per sweep is L1,L2,L3,L4, but
    // L4(sweep it) and L1(sweep it+1) are mutually independent (L4 reads s3,
    // L1 reads s2 + c1f) -> merged into one dispatch. ---
    gemm_splitk_kernel<<<512, blk, 0, stream>>>(jL1, jL1, 512);          // L1, sweep 0
    for (int it = 0; it < 25; ++it) {
        gemm_splitk_kernel<<<512, blk, 0, stream>>>(jL2, jL2, 512);
        gemm_splitk_kernel<<<512, blk, 0, stream>>>(jL3, jL3, 512);
        if (it < 24) {
            gemm_splitk_kernel<<<1024, blk, 0, stream>>>(jL4, jL1, 512); // L4 + next L1
        } else {
            gemm_splitk_kernel<<<512, blk, 0, stream>>>(jL4f, jL4f, 512);
        }
    }
}

// Round 5
// 2610.104 us; speedup vs baseline: 5.4549x; 5.4549x over previous
//
#include <hip/hip_runtime.h>

typedef _Float16 fp16_t;
typedef _Float16 v8h  __attribute__((ext_vector_type(8)));
typedef float    v16f __attribute__((ext_vector_type(16)));

#define RELAX_LR 0.3f

// async global->LDS, 16B per lane. LDS dest = wave-uniform base + lane*16.
__device__ __forceinline__ void async_cp16(const void* g, void* l) {
    __builtin_amdgcn_global_load_lds(
        (const __attribute__((address_space(1))) void*)g,
        (__attribute__((address_space(3))) void*)l, 16, 0, 0);
}

// GEMM job: C_partial(z) = A1*B1t^T (concat K-space [0,K1)) ++ A2*B2t^T
// ([K1,K1+K2s)). Chunk z covers [z*CK,(z+1)*CK) and MAY cross the section
// boundary (both K1 and chunks are multiples of BK=64, so a BK-tile never
// straddles; pointer select per BK-iter is block-uniform scalar work).
struct GJob {
    const fp16_t *A1, *B1t, *A2, *B2t;
    fp16_t* part;
    int K1, K2s, CK, Ntot;
};

// ---------------------------------------------------------------------------
// Two-job split-K GEMM into fp16 partials (fp32 MFMA accumulate, one rounding
// at store). Blocks [0,nb0) run j0, [nb0,grid) run j1. Tile BM=128 x BN=128 x
// BK=64, 256 thr = 4 waves, each wave 64x64. r5 change vs the 2407us r0 core:
// wave tile computed as 2x2 v_mfma_f32_32x32x16_f16 (16 MFMA/tile @ ~8cyc vs
// 32 @ ~5cyc; ubench 2382 vs 2075 TF) instead of 4x4 16x16x32. The 32-row
// read pattern needs a bank swizzle: LDS 16B-slot ^= (row&3), applied as
// pre-swizzled GLOBAL source in staging (global_load_lds dest stays linear,
// rule both-sides-or-neither) + XOR'd col on ds_read. Coalescing unchanged
// (4-lane groups still cover one 64B line, permuted within).
// Sync structure, z-split, XCD decode identical to r0 (fence-free: r4 showed
// per-block device fences collapse perf 6x via L2 invalidate storms).
// ---------------------------------------------------------------------------
__global__ __launch_bounds__(256, 2) void gemm_splitk_kernel(GJob j0, GJob j1, int nb0)
{
    __shared__ __align__(16) fp16_t As[2][2][128][32];  // [stage][khalf][row][col]
    __shared__ __align__(16) fp16_t Bs[2][2][128][32];

    const int tid  = threadIdx.x;
    const int lane = tid & 63;
    const int w    = tid >> 6;         // wave 0..3
    const int wm   = w >> 1;           // m-half (64 rows)
    const int wn   = w & 1;            // n-half (64 cols)
    const int l31  = lane & 31;
    const int g    = lane >> 5;        // k-half selector within a 16-K step

    int bblk = blockIdx.x;
    const GJob j = (bblk < nb0) ? j0 : j1;       // block-uniform
    if (bblk >= nb0) bblk -= nb0;

    // swizzled decode: bblk%8 = XCD; c = (bn,z) combo pinned to one XCD.
    const int low3 = bblk & 7;
    const int gg   = bblk >> 3;
    const int bm   = gg & 7;
    const int c    = (gg >> 3) * 8 + low3;  // 0..63
    int bn, z;
    if (j.Ntot == 2048) { bn = c >> 2; z = c & 3; }   // 16 bn x 4 z
    else                { bn = c >> 3; z = c & 7; }   // 8 bn x 8 z
    const int k0 = z * j.CK;

    // staging: each cp16 = 16 rows x 32 fp16 (1 KB/wave), lane -> (row=lane/4,
    // LDS slot=lane&3). Pre-swizzled global source: the element block that
    // belongs in LDS slot q of row r is global col-slot q^(r&3) (so reads at
    // slot p^(r&3) return logical slot p). 4-lane groups still fetch one full
    // 64B line. Wave w owns rows [32w,32w+32) of A and B for both khalves.
    const int sr = lane >> 2;
    const int sc = (((lane & 3) ^ (sr & 3))) * 8;
    const size_t rowA = (size_t)(bm * 128 + 32 * w + sr);
    const size_t rowB = (size_t)(bn * 128 + 32 * w + sr);
    const fp16_t* a1 = j.A1  + rowA * j.K1 + sc;
    const fp16_t* b1 = j.B1t + rowB * j.K1 + sc;
    const fp16_t* a2 = j.A2  ? j.A2  + rowA * j.K2s + sc : nullptr;
    const fp16_t* b2 = j.B2t ? j.B2t + rowB * j.K2s + sc : nullptr;
    const size_t s16a = (size_t)16 * j.K1;
    const size_t s16b = (size_t)16 * j.K2s;

    auto stage = [&](int buf, int kc) {
        const fp16_t *a0, *b0; size_t st;
        if (kc < j.K1) { a0 = a1 + kc;          b0 = b1 + kc;          st = s16a; }
        else           { a0 = a2 + (kc - j.K1); b0 = b2 + (kc - j.K1); st = s16b; }
        async_cp16(a0,           &As[buf][0][32 * w     ][0]);
        async_cp16(a0 + st,      &As[buf][0][32 * w + 16][0]);
        async_cp16(a0 + 32,      &As[buf][1][32 * w     ][0]);
        async_cp16(a0 + 32 + st, &As[buf][1][32 * w + 16][0]);
        async_cp16(b0,           &Bs[buf][0][32 * w     ][0]);
        async_cp16(b0 + st,      &Bs[buf][0][32 * w + 16][0]);
        async_cp16(b0 + 32,      &Bs[buf][1][32 * w     ][0]);
        async_cp16(b0 + 32 + st, &Bs[buf][1][32 * w + 16][0]);
    };

    v16f acc[2][2] = {};
    const int iters = j.CK >> 6;       // BK = 64

    stage(0, k0);                      // prologue: tile 0 -> buffer 0

    for (int it = 0; it < iters; ++it) {
        __syncthreads();   // drains vmcnt -> buf (it&1) ready; prior ds_reads done
        if (it + 1 < iters) stage((it + 1) & 1, k0 + (it + 1) * 64);
        const int cur = it & 1;
        #pragma unroll
        for (int s = 0; s < 4; ++s) {              // four 16-K steps
            const int h  = s >> 1;                 // khalf
            // logical slot = (s&1)*2 + g; stored at slot ^ (row&3); row&3 == l31&3
            const int cs = ((((s & 1) * 2 + g) ^ (l31 & 3))) * 8;
            const v8h a0v = *(const v8h*)&As[cur][h][wm * 64      + l31][cs];
            const v8h a1v = *(const v8h*)&As[cur][h][wm * 64 + 32 + l31][cs];
            const v8h b0v = *(const v8h*)&Bs[cur][h][wn * 64      + l31][cs];
            const v8h b1v = *(const v8h*)&Bs[cur][h][wn * 64 + 32 + l31][cs];
            acc[0][0] = __builtin_amdgcn_mfma_f32_32x32x16_f16(a0v, b0v, acc[0][0], 0, 0, 0);
            acc[0][1] = __builtin_amdgcn_mfma_f32_32x32x16_f16(a0v, b1v, acc[0][1], 0, 0, 0);
            acc[1][0] = __builtin_amdgcn_mfma_f32_32x32x16_f16(a1v, b0v, acc[1][0], 0, 0, 0);
            acc[1][1] = __builtin_amdgcn_mfma_f32_32x32x16_f16(a1v, b1v, acc[1][1], 0, 0, 0);
        }
    }

    // write fp16 partials. 32x32 C/D layout (HW-verified):
    // col = lane&31, row = (reg&3) + 8*(reg>>2) + 4*(lane>>5).
    fp16_t* po = j.part + (size_t)z * 1024 * j.Ntot;
    const int rowb = bm * 128 + wm * 64 + g * 4;
    const int colb = bn * 128 + wn * 64 + l31;
    #pragma unroll
    for (int fm2 = 0; fm2 < 2; ++fm2)
        #pragma unroll
        for (int fn2 = 0; fn2 < 2; ++fn2) {
            const int col = colb + fn2 * 32;
            #pragma unroll
            for (int r = 0; r < 16; ++r) {
                const int row = rowb + fm2 * 32 + (r & 3) + 8 * (r >> 2);
                po[(size_t)row * j.Ntot + col] = (fp16_t)acc[fm2][fn2][r];
            }
        }
}

// Reduce job: sum nz fp16 partial slices + (bias[col] OR per-element fp32
// extra), optional relax-update vs s_old, clip, fp16 state write; optional
// fp32 final output stripped to [1024,1000].
struct RJob {
    const fp16_t* part;
    const float* bias;
    const float* extra;
    const fp16_t* s_old;
    fp16_t* outb;
    float* finout;
    int nz, Ntot, do_update;
};

__global__ __launch_bounds__(256) void reduce_update_kernel(RJob j0, RJob j1, int nb0)
{
    int b = blockIdx.x;
    const RJob j = (b < nb0) ? j0 : j1;          // block-uniform
    if (b >= nb0) b -= nb0;
    const size_t e = ((size_t)b * 256 + threadIdx.x) * 8;  // grids sized exactly

    float v[8];
    {
        const v8h p0 = *(const v8h*)(j.part + e);
        #pragma unroll
        for (int k = 0; k < 8; ++k) v[k] = (float)p0[k];
    }
    for (int z = 1; z < j.nz; ++z) {
        const v8h p = *(const v8h*)(j.part + (size_t)z * 1024 * j.Ntot + e);
        #pragma unroll
        for (int k = 0; k < 8; ++k) v[k] += (float)p[k];
    }
    const int col = (int)e & (j.Ntot - 1);
    if (j.extra) {
        const float4 e0 = *(const float4*)(j.extra + e);
        const float4 e1 = *(const float4*)(j.extra + e + 4);
        v[0] += e0.x; v[1] += e0.y; v[2] += e0.z; v[3] += e0.w;
        v[4] += e1.x; v[5] += e1.y; v[6] += e1.z; v[7] += e1.w;
    } else {
        const float4 b0 = *(const float4*)(j.bias + col);
        const float4 b1 = *(const float4*)(j.bias + col + 4);
        v[0] += b0.x; v[1] += b0.y; v[2] += b0.z; v[3] += b0.w;
        v[4] += b1.x; v[5] += b1.y; v[6] += b1.z; v[7] += b1.w;
    }
    if (j.do_update) {
        const v8h so = *(const v8h*)(j.s_old + e);
        #pragma unroll
        for (int k = 0; k < 8; ++k) {
            const float s = (float)so[k];
            v[k] = s + RELAX_LR * (v[k] - s);
        }
    }
    #pragma unroll
    for (int k = 0; k < 8; ++k) v[k] = fminf(fmaxf(v[k], 0.f), 1.f);
    v8h h;
    #pragma unroll
    for (int k = 0; k < 8; ++k) h[k] = (fp16_t)v[k];
    *(v8h*)(j.outb + e) = h;

    if (j.finout && col < 1000) {
        const int row = (int)(e >> 10);          // Ntot == 1024 on this path
        float* o = j.finout + (size_t)row * 1000 + col;
        float4 o0 = {v[0], v[1], v[2], v[3]};
        float4 o1 = {v[4], v[5], v[6], v[7]};
        *(float4*)o       = o0;
        *(float4*)(o + 4) = o1;
    }
}

// c1f = sum of 4 fp16 partial slices + bias (fp32, no clip): the
// loop-invariant layer-1 constant b1 + rho(x)@W0, computed once.
__global__ __launch_bounds__(256) void makec1_kernel(
    const fp16_t* __restrict__ part, const float* __restrict__ bias,
    float* __restrict__ c1f, int total8)
{
    const int i = blockIdx.x * 256 + threadIdx.x;
    if (i >= total8) return;
    const size_t e = (size_t)i * 8;
    float v[8];
    {
        const v8h p0 = *(const v8h*)(part + e);
        #pragma unroll
        for (int k = 0; k < 8; ++k) v[k] = (float)p0[k];
    }
    #pragma unroll
    for (int z = 1; z < 4; ++z) {
        const v8h p = *(const v8h*)(part + (size_t)z * 1024 * 2048 + e);
        #pragma unroll
        for (int k = 0; k < 8; ++k) v[k] += (float)p[k];
    }
    const int col = (int)e & 2047;
    const float4 b0 = *(const float4*)(bias + col);
    const float4 b1 = *(const float4*)(bias + col + 4);
    v[0] += b0.x; v[1] += b0.y; v[2] += b0.z; v[3] += b0.w;
    v[4] += b1.x; v[5] += b1.y; v[6] += b1.z; v[7] += b1.w;
    float4 o0 = {v[0], v[1], v[2], v[3]};
    float4 o1 = {v[4], v[5], v[6], v[7]};
    *(float4*)(c1f + e)     = o0;
    *(float4*)(c1f + e + 4) = o1;
}

// fp32 W [R,C] -> fp16 Wb [Rp,Cp] (optional) + fp16 WbT [Cp,Rp], zero-padded.
__global__ void conv_w_kernel(const float* __restrict__ W, int R, int C,
                              fp16_t* Wb, fp16_t* __restrict__ WbT,
                              int Rp, int Cp)
{
    __shared__ float t[32][33];
    const int tx = threadIdx.x & 31;
    const int ty = threadIdx.x >> 5;   // 0..7
    const int r0 = blockIdx.y * 32;
    const int c0 = blockIdx.x * 32;
    #pragma unroll
    for (int i = 0; i < 4; ++i) {
        const int r = r0 + ty + i * 8;
        const int c = c0 + tx;
        float v = 0.f;
        if (r < R && c < C) v = W[(size_t)r * C + c];
        t[ty + i * 8][tx] = v;
    }
    __syncthreads();
    if (Wb) {
        #pragma unroll
        for (int i = 0; i < 4; ++i) {
            const int r = r0 + ty + i * 8;
            const int c = c0 + tx;
            if (r < Rp && c < Cp) Wb[(size_t)r * Cp + c] = (fp16_t)t[ty + i * 8][tx];
        }
    }
    #pragma unroll
    for (int i = 0; i < 4; ++i) {
        const int cc = c0 + ty + i * 8;
        const int rr = r0 + tx;
        if (cc < Cp && rr < Rp) WbT[(size_t)cc * Rp + rr] = (fp16_t)t[tx][ty + i * 8];
    }
}

__global__ void conv_x_kernel(const float* __restrict__ x,
                              fp16_t* __restrict__ xb, fp16_t* __restrict__ rxb, int n)
{
    const int i = blockIdx.x * blockDim.x + threadIdx.x;
    if (i < n) {
        const float v = x[i];
        xb[i]  = (fp16_t)v;
        rxb[i] = (fp16_t)fminf(fmaxf(v, 0.f), 1.f);
    }
}

__global__ void pad_b4_kernel(const float* __restrict__ b4, float* __restrict__ b4p)
{
    const int i = blockIdx.x * blockDim.x + threadIdx.x;
    if (i < 1024) b4p[i] = (i < 1000) ? b4[i] : 0.f;
}

extern "C" void kernel_launch(void* const* d_in, const int* in_sizes, int n_in,
                              void* d_out, int out_size, void* d_ws, size_t ws_size,
                              hipStream_t stream)
{
    const float* x  = (const float*)d_in[0];
    const float* W0 = (const float*)d_in[1];
    const float* W1 = (const float*)d_in[2];
    const float* W2 = (const float*)d_in[3];
    const float* W3 = (const float*)d_in[4];
    const float* b1 = (const float*)d_in[5];
    const float* b2 = (const float*)d_in[6];
    const float* b3 = (const float*)d_in[7];
    const float* b4 = (const float*)d_in[8];
    float* out = (float*)d_out;

    char* p = (char*)d_ws;
    auto alloc = [&](size_t bytes) {
        char* q = p;
        p += (bytes + 255) & ~(size_t)255;
        return q;
    };

    fp16_t* xb    = (fp16_t*)alloc((size_t)1024 * 2048 * 2);
    fp16_t* rxb   = (fp16_t*)alloc((size_t)1024 * 2048 * 2);
    fp16_t* Wb1   = (fp16_t*)alloc((size_t)2048 * 2048 * 2);
    fp16_t* Wb2   = (fp16_t*)alloc((size_t)2048 * 2048 * 2);
    fp16_t* Wb3   = (fp16_t*)alloc((size_t)2048 * 1024 * 2);   // padded cols
    fp16_t* WbT0  = (fp16_t*)alloc((size_t)2048 * 2048 * 2);
    fp16_t* WbT1  = (fp16_t*)alloc((size_t)2048 * 2048 * 2);
    fp16_t* WbT2  = (fp16_t*)alloc((size_t)2048 * 2048 * 2);
    fp16_t* WbT3  = (fp16_t*)alloc((size_t)1024 * 2048 * 2);   // padded rows
    fp16_t* s1b   = (fp16_t*)alloc((size_t)1024 * 2048 * 2);
    fp16_t* s2b   = (fp16_t*)alloc((size_t)1024 * 2048 * 2);
    fp16_t* s3b   = (fp16_t*)alloc((size_t)1024 * 2048 * 2);
    fp16_t* s4b   = (fp16_t*)alloc((size_t)1024 * 1024 * 2);
    float*  b4p   = (float*)alloc(1024 * 4);
    float*  c1f   = (float*)alloc((size_t)1024 * 2048 * 4);    // hoisted b1+rho(x)@W0
    fp16_t* partA = (fp16_t*)alloc((size_t)8 * 1024 * 1024 * 2); // 16 MB (L4 jobs)
    fp16_t* partB = (fp16_t*)alloc((size_t)4 * 1024 * 2048 * 2); // 16 MB (L1-3 jobs)
    (void)ws_size; (void)in_sizes; (void)n_in; (void)out_size;

    // --- setup conversions ---
    conv_x_kernel<<<(1024 * 2048 + 255) / 256, 256, 0, stream>>>(x, xb, rxb, 1024 * 2048);
    pad_b4_kernel<<<4, 256, 0, stream>>>(b4, b4p);
    conv_w_kernel<<<dim3(64, 64), 256, 0, stream>>>(W0, 2048, 2048, nullptr, WbT0, 2048, 2048);
    conv_w_kernel<<<dim3(64, 64), 256, 0, stream>>>(W1, 2048, 2048, Wb1, WbT1, 2048, 2048);
    conv_w_kernel<<<dim3(64, 64), 256, 0, stream>>>(W2, 2048, 2048, Wb2, WbT2, 2048, 2048);
    conv_w_kernel<<<dim3(32, 64), 256, 0, stream>>>(W3, 2048, 1000, Wb3, WbT3, 2048, 1024);

    const dim3 blk(256);
    const int rg2048 = 1024 * 2048 / 8 / 256;   // 1024 blocks
    const int rg1024 = 1024 * 1024 / 8 / 256;   // 512 blocks

    // --- GEMM jobs (A1,B1t,A2,B2t,part,K1,K2s,CK,Ntot) ---
    const GJob jC1 = { rxb, WbT0, nullptr, nullptr, partA, 2048, 0,    512,  2048 };
    const GJob jI1 = { xb,  WbT0, nullptr, nullptr, partB, 2048, 0,    512,  2048 };
    const GJob jI2 = { s1b, WbT1, nullptr, nullptr, partB, 2048, 0,    512,  2048 };
    const GJob jI3 = { s2b, WbT2, nullptr, nullptr, partB, 2048, 0,    512,  2048 };
    const GJob jI4 = { s3b, WbT3, nullptr, nullptr, partA, 2048, 0,    256,  1024 };
    const GJob jL1 = { s2b, Wb1,  nullptr, nullptr, partB, 2048, 0,    512,  2048 };
    const GJob jL2 = { s1b, WbT1, s3b, Wb2,         partB, 2048, 2048, 1024, 2048 };
    const GJob jL3 = { s2b, WbT2, s4b, Wb3,         partB, 2048, 1024, 768,  2048 }; // balanced 4x768, chunk 2 crosses
    const GJob jL4 = { s3b, WbT3, nullptr, nullptr, partA, 2048, 0,    256,  1024 };

    // --- reduce jobs (part,bias,extra,s_old,outb,finout,nz,Ntot,do_update) ---
    const RJob rI1 = { partB, b1,  nullptr, nullptr, s1b, nullptr, 4, 2048, 0 };
    const RJob rI2 = { partB, b2,  nullptr, nullptr, s2b, nullptr, 4, 2048, 0 };
    const RJob rI3 = { partB, b3,  nullptr, nullptr, s3b, nullptr, 4, 2048, 0 };
    const RJob rI4 = { partA, b4p, nullptr, nullptr, s4b, nullptr, 8, 1024, 0 };
    const RJob rL1 = { partB, nullptr, c1f, s1b, s1b, nullptr, 4, 2048, 1 };
    const RJob rL2 = { partB, b2,  nullptr, s2b, s2b, nullptr, 4, 2048, 1 };
    const RJob rL3 = { partB, b3,  nullptr, s3b, s3b, nullptr, 4, 2048, 1 };
    const RJob rL4 = { partA, b4p, nullptr, s4b, s4b, nullptr, 8, 1024, 1 };
    RJob rL4f = rL4; rL4f.finout = out;

    // --- hoisted layer-1 constant: c1f = b1 + rho(x)@W0 (once, reused 25x) ---
    gemm_splitk_kernel<<<512, blk, 0, stream>>>(jC1, jC1, 512);
    makec1_kernel<<<rg2048, blk, 0, stream>>>(partA, b1, c1f, 1024 * 2048 / 8);

    // --- feedforward init: s_l = clip(s_{l-1} @ W_{l-1} + b_l) ---
    gemm_splitk_kernel<<<512, blk, 0, stream>>>(jI1, jI1, 512);
    reduce_update_kernel<<<rg2048, blk, 0, stream>>>(rI1, rI1, rg2048);
    gemm_splitk_kernel<<<512, blk, 0, stream>>>(jI2, jI2, 512);
    reduce_update_kernel<<<rg2048, blk, 0, stream>>>(rI2, rI2, rg2048);
    gemm_splitk_kernel<<<512, blk, 0, stream>>>(jI3, jI3, 512);
    reduce_update_kernel<<<rg2048, blk, 0, stream>>>(rI3, rI3, rg2048);
    gemm_splitk_kernel<<<512, blk, 0, stream>>>(jI4, jI4, 512);
    reduce_update_kernel<<<rg1024, blk, 0, stream>>>(rI4, rI4, rg1024);

    // --- 25 Gauss-Seidel sweeps. Layer order per sweep is L1,L2,L3,L4, but
    // L4(sweep it) and L1(sweep it+1) are mutually independent (L4 reads s3,
    // L1 reads s2 + c1f) -> merged into one GEMM + one reduce dispatch. ---
    gemm_splitk_kernel<<<512, blk, 0, stream>>>(jL1, jL1, 512);          // L1, sweep 0
    reduce_update_kernel<<<rg2048, blk, 0, stream>>>(rL1, rL1, rg2048);
    for (int it = 0; it < 25; ++it) {
        gemm_splitk_kernel<<<512, blk, 0, stream>>>(jL2, jL2, 512);
        reduce_update_kernel<<<rg2048, blk, 0, stream>>>(rL2, rL2, rg2048);
        gemm_splitk_kernel<<<512, blk, 0, stream>>>(jL3, jL3, 512);
        reduce_update_kernel<<<rg2048, blk, 0, stream>>>(rL3, rL3, rg2048);
        if (it < 24) {
            gemm_splitk_kernel<<<1024, blk, 0, stream>>>(jL4, jL1, 512); // L4 + next L1
            reduce_update_kernel<<<rg1024 + rg2048, blk, 0, stream>>>(rL4, rL1, rg1024);
        } else {
            gemm_splitk_kernel<<<512, blk, 0, stream>>>(jL4, jL4, 512);
            reduce_update_kernel<<<rg1024, blk, 0, stream>>>(rL4f, rL4f, rg1024);
        }
    }
}